// Round 1
// baseline (7202.085 us; speedup 1.0000x reference)
//
#include <hip/hip_runtime.h>
#include <math.h>

#define T_LEN 4096
#define EMB 300
#define DIN 1200
#define HID 256
#define G4 1024           // 4*HID gate rows per direction
#define NTAG 12
#define START_TAG 10
#define STOP_TAG 11
#define NEGV -10000.0f

#if defined(__has_builtin)
#  if __has_builtin(__builtin_amdgcn_sdot4)
#    define HAVE_SDOT4 1
#  endif
#endif

__device__ __forceinline__ int sdot4(int a, int b, int c) {
#ifdef HAVE_SDOT4
  return __builtin_amdgcn_sdot4(a, b, c, false);
#else
  return c + (int)(char)(a) * (int)(char)(b)
           + (int)(char)(a >> 8) * (int)(char)(b >> 8)
           + (int)(char)(a >> 16) * (int)(char)(b >> 16)
           + (a >> 24) * (b >> 24);
#endif
}

__device__ __forceinline__ float sigm(float x) { return 1.0f / (1.0f + __expf(-x)); }
__device__ __forceinline__ float tanh_fast(float x) {
  x = fminf(fmaxf(x, -15.0f), 15.0f);
  float e = __expf(2.0f * x);
  return (e - 1.0f) / (e + 1.0f);
}

// ---------------------------------------------------------------------------
// Quantize w_hh (both directions) to int8, per-row scale. Row r: 256 f32 ->
// 64 packed int32 (little-endian byte order matches v_dot4_i32_i8).
// fac[row] = maxabs/(127*127): preact_rec = fac * (int32 dot of qw,qh).
// ---------------------------------------------------------------------------
__global__ __launch_bounds__(64) void quant_whh(const float* __restrict__ w_hh_f,
                                                const float* __restrict__ w_hh_b,
                                                int* __restrict__ qw,
                                                float* __restrict__ fac) {
  int row = blockIdx.x;   // 0..2047 (fwd rows 0..1023, bwd 1024..2047)
  int tid = threadIdx.x;  // 0..63
  const float* src = (row < G4) ? (w_hh_f + (size_t)row * HID)
                                : (w_hh_b + (size_t)(row - G4) * HID);
  float4 v = *(const float4*)(src + tid * 4);
  float m = fmaxf(fmaxf(fabsf(v.x), fabsf(v.y)), fmaxf(fabsf(v.z), fabsf(v.w)));
#pragma unroll
  for (int off = 32; off > 0; off >>= 1) m = fmaxf(m, __shfl_xor(m, off, 64));
  float inv = (m > 0.f) ? 127.0f / m : 0.f;
  int q0 = (int)rintf(v.x * inv), q1 = (int)rintf(v.y * inv);
  int q2 = (int)rintf(v.z * inv), q3 = (int)rintf(v.w * inv);
  qw[(size_t)row * 64 + tid] =
      (q0 & 255) | ((q1 & 255) << 8) | ((q2 & 255) << 16) | ((q3 & 255) << 24);
  if (tid == 0) fac[row] = m / (127.0f * 127.0f);
}

// ---------------------------------------------------------------------------
// xg[t][j] = emb_row(t) . w_ih[j] + b_ih[j] + b_hh[j];  j<1024 fwd, else bwd.
// Embedding gather fused into A-tile staging (emb row = concat of 4 W_emb
// rows of 300; 300%4==0 so float4 loads never cross a segment boundary).
// BM=128 (t), BN=64 (j), BK=16, 256 threads, 8x4 outputs/thread, f32.
// ---------------------------------------------------------------------------
__global__ __launch_bounds__(256) void xg_gemm(
    const int* __restrict__ words0, const int* __restrict__ words1,
    const int* __restrict__ words2, const int* __restrict__ words3,
    const float* __restrict__ W_emb,
    const float* __restrict__ w_ih_f, const float* __restrict__ w_ih_b,
    const float* __restrict__ b_ih_f, const float* __restrict__ b_hh_f,
    const float* __restrict__ b_ih_b, const float* __restrict__ b_hh_b,
    float* __restrict__ xg) {
  __shared__ __align__(16) float As[16][132];  // [k][t-row], 132: pad, 528B row = 16B-mult
  __shared__ __align__(16) float Bs[16][68];   // [k][j-row]
  __shared__ int w4[128][4];
  int tid = threadIdx.x;
  int t0 = blockIdx.x * 128;
  int n0 = blockIdx.y * 64;
  if (tid < 128) {
    int t = t0 + tid;
    w4[tid][0] = words0[t]; w4[tid][1] = words1[t];
    w4[tid][2] = words2[t]; w4[tid][3] = words3[t];
  }
  int kq = tid & 3;   // float4 slot within the 16-wide k tile
  int r  = tid >> 2;  // 0..63
  const float* Bp = (n0 < G4) ? (w_ih_f + (size_t)(n0 + r) * DIN)
                              : (w_ih_b + (size_t)(n0 + r - G4) * DIN);
  float acc[8][4];
#pragma unroll
  for (int m = 0; m < 8; ++m)
#pragma unroll
    for (int n = 0; n < 4; ++n) acc[m][n] = 0.f;
  __syncthreads();  // w4 ready

  for (int it = 0; it < 75; ++it) {
    int kk = it * 16 + kq * 4;
    int seg = (kk >= 900) ? 3 : (kk >= 600) ? 2 : (kk >= 300) ? 1 : 0;
    int col = kk - seg * 300;
    int wid0 = w4[r][seg];
    int wid1 = w4[r + 64][seg];
    float4 a0 = *(const float4*)(W_emb + (size_t)wid0 * EMB + col);
    float4 a1 = *(const float4*)(W_emb + (size_t)wid1 * EMB + col);
    float4 b  = *(const float4*)(Bp + kk);
    As[kq * 4 + 0][r] = a0.x; As[kq * 4 + 1][r] = a0.y;
    As[kq * 4 + 2][r] = a0.z; As[kq * 4 + 3][r] = a0.w;
    As[kq * 4 + 0][r + 64] = a1.x; As[kq * 4 + 1][r + 64] = a1.y;
    As[kq * 4 + 2][r + 64] = a1.z; As[kq * 4 + 3][r + 64] = a1.w;
    Bs[kq * 4 + 0][r] = b.x; Bs[kq * 4 + 1][r] = b.y;
    Bs[kq * 4 + 2][r] = b.z; Bs[kq * 4 + 3][r] = b.w;
    __syncthreads();
    int ii = (tid & 15) * 8;
    int jj = (tid >> 4) * 4;
#pragma unroll
    for (int k2 = 0; k2 < 16; ++k2) {
      float4 av0 = *(const float4*)&As[k2][ii];
      float4 av1 = *(const float4*)&As[k2][ii + 4];
      float4 bv  = *(const float4*)&Bs[k2][jj];
      float a[8] = {av0.x, av0.y, av0.z, av0.w, av1.x, av1.y, av1.z, av1.w};
      float bb[4] = {bv.x, bv.y, bv.z, bv.w};
#pragma unroll
      for (int m = 0; m < 8; ++m)
#pragma unroll
        for (int n = 0; n < 4; ++n) acc[m][n] = fmaf(a[m], bb[n], acc[m][n]);
    }
    __syncthreads();
  }
  int ii = (tid & 15) * 8;
  int jj = (tid >> 4) * 4;
  float bias[4];
#pragma unroll
  for (int n = 0; n < 4; ++n) {
    int jg = n0 + jj + n;
    bias[n] = (jg < G4) ? (b_ih_f[jg] + b_hh_f[jg])
                        : (b_ih_b[jg - G4] + b_hh_b[jg - G4]);
  }
#pragma unroll
  for (int m = 0; m < 8; ++m) {
    int row = t0 + ii + m;
    float4 st = make_float4(acc[m][0] + bias[0], acc[m][1] + bias[1],
                            acc[m][2] + bias[2], acc[m][3] + bias[3]);
    *(float4*)(xg + (size_t)row * 2048 + n0 + jj) = st;
  }
}

// ---------------------------------------------------------------------------
// LSTM recurrence, one block per direction, 256 threads (4 waves, 1/SIMD,
// <=512 VGPR budget). Thread k owns ALL FOUR gate rows of hidden unit k
// (rows k, 256+k, 512+k, 768+k) as int8 weights in registers (256 VGPRs),
// so c/h update is thread-local. h is shared as packed int8 in LDS,
// double-buffered -> ONE barrier per step. Matvec = 256 sdot4/thread.
// ---------------------------------------------------------------------------
__global__ __launch_bounds__(256, 1) void lstm_rec(
    const float* __restrict__ xg, const int* __restrict__ qw,
    const float* __restrict__ fac, float* __restrict__ hf,
    float* __restrict__ hb) {
  int dir = blockIdx.x;
  int k = threadIdx.x;  // hidden unit
  __shared__ __align__(16) int hq[2][64];
  int w[4][64];
  float fr[4];
#pragma unroll
  for (int g = 0; g < 4; ++g) {
    int row = dir * G4 + g * HID + k;
    fr[g] = fac[row];
    const int* src = qw + (size_t)row * 64;
#pragma unroll
    for (int j = 0; j < 64; ++j) w[g][j] = src[j];
  }
  float* hout = dir ? hb : hf;
  const float* xbase = xg + dir * G4;
  float c = 0.f;
  if (k < 64) hq[0][k] = 0;
  __syncthreads();
  float xv[4], xn[4];
  {
    int t = dir ? (T_LEN - 1) : 0;
#pragma unroll
    for (int g = 0; g < 4; ++g) xv[g] = xbase[(size_t)t * 2048 + g * HID + k];
  }
  for (int s = 0; s < T_LEN; ++s) {
    int t = dir ? (T_LEN - 1 - s) : s;
    // prefetch next step's xg row (independent of h -> overlaps matvec)
#pragma unroll
    for (int g = 0; g < 4; ++g) xn[g] = 0.f;
    if (s + 1 < T_LEN) {
      int tn = dir ? (T_LEN - 2 - s) : (s + 1);
#pragma unroll
      for (int g = 0; g < 4; ++g) xn[g] = xbase[(size_t)tn * 2048 + g * HID + k];
    }
    const int* hc = hq[s & 1];
    int acc0 = 0, acc1 = 0, acc2 = 0, acc3 = 0;
#pragma unroll
    for (int j = 0; j < 16; ++j) {
      int4 hv = *(const int4*)(hc + j * 4);  // uniform-address broadcast read
      acc0 = sdot4(w[0][j * 4 + 0], hv.x, acc0);
      acc1 = sdot4(w[1][j * 4 + 0], hv.x, acc1);
      acc2 = sdot4(w[2][j * 4 + 0], hv.x, acc2);
      acc3 = sdot4(w[3][j * 4 + 0], hv.x, acc3);
      acc0 = sdot4(w[0][j * 4 + 1], hv.y, acc0);
      acc1 = sdot4(w[1][j * 4 + 1], hv.y, acc1);
      acc2 = sdot4(w[2][j * 4 + 1], hv.y, acc2);
      acc3 = sdot4(w[3][j * 4 + 1], hv.y, acc3);
      acc0 = sdot4(w[0][j * 4 + 2], hv.z, acc0);
      acc1 = sdot4(w[1][j * 4 + 2], hv.z, acc1);
      acc2 = sdot4(w[2][j * 4 + 2], hv.z, acc2);
      acc3 = sdot4(w[3][j * 4 + 2], hv.z, acc3);
      acc0 = sdot4(w[0][j * 4 + 3], hv.w, acc0);
      acc1 = sdot4(w[1][j * 4 + 3], hv.w, acc1);
      acc2 = sdot4(w[2][j * 4 + 3], hv.w, acc2);
      acc3 = sdot4(w[3][j * 4 + 3], hv.w, acc3);
    }
    float pi = xv[0] + fr[0] * (float)acc0;
    float pf = xv[1] + fr[1] * (float)acc1;
    float pg = xv[2] + fr[2] * (float)acc2;
    float po = xv[3] + fr[3] * (float)acc3;
    float iv = sigm(pi), fg = sigm(pf), gv = tanh_fast(pg), ov = sigm(po);
    c = fg * c + iv * gv;
    float h = ov * tanh_fast(c);
    hout[(size_t)t * HID + k] = h;
    int qh = (int)rintf(h * 127.0f);  // |h| < 1 -> fits int8
    ((char*)hq[(s + 1) & 1])[k] = (char)qh;
#pragma unroll
    for (int g = 0; g < 4; ++g) xv[g] = xn[g];
    __syncthreads();  // next buffer published; old buffer free to overwrite
  }
}

// ---------------------------------------------------------------------------
// feats[t][k] = W_tag[k] . [hf[t]; hb[t]] + b_tag[k]; one wave per (t,k).
// ---------------------------------------------------------------------------
__global__ __launch_bounds__(256) void feats_k(const float* __restrict__ W_tag,
                                               const float* __restrict__ b_tag,
                                               const float* __restrict__ hf,
                                               const float* __restrict__ hb,
                                               float* __restrict__ feats) {
  int pair = blockIdx.x * 4 + (threadIdx.x >> 6);
  int lane = threadIdx.x & 63;
  int t = pair / NTAG;
  int k = pair % NTAG;
  float s = 0.f;
#pragma unroll
  for (int i = 0; i < 4; ++i) {
    int j = i * 64 + lane;
    s = fmaf(W_tag[k * 512 + j], hf[(size_t)t * HID + j], s);
  }
#pragma unroll
  for (int i = 4; i < 8; ++i) {
    int j = i * 64 + lane;
    s = fmaf(W_tag[k * 512 + j], hb[(size_t)t * HID + (j - 256)], s);
  }
#pragma unroll
  for (int off = 32; off > 0; off >>= 1) s += __shfl_xor(s, off, 64);
  if (lane == 0) feats[t * NTAG + k] = s + b_tag[k];
}

// ---------------------------------------------------------------------------
// Viterbi: lane k (<12) holds fv[k]; strict-> ascending scans match
// jnp.argmax first-max tie rule. Backpointers in LDS; lane-0 backtrace.
// Output: d_out[0]=score, d_out[1..4096]=path (as f32).
// ---------------------------------------------------------------------------
__global__ __launch_bounds__(64) void viterbi_k(const float* __restrict__ feats,
                                                const float* __restrict__ trans,
                                                float* __restrict__ out) {
  __shared__ unsigned char bpL[T_LEN * NTAG];
  int k = threadIdx.x;
  bool act = k < NTAG;
  float trc[NTAG];
#pragma unroll
  for (int p = 0; p < NTAG; ++p) trc[p] = act ? trans[k * NTAG + p] : NEGV;
  float fv = (act && k == START_TAG) ? 0.f : NEGV;
  float ft = act ? feats[k] : 0.f;
  for (int t = 0; t < T_LEN; ++t) {
    float ftn = (act && t + 1 < T_LEN) ? feats[(t + 1) * NTAG + k] : 0.f;
    float v[NTAG];
#pragma unroll
    for (int p = 0; p < NTAG; ++p) v[p] = __shfl(fv, p, 64) + trc[p];
    float bv = v[0];
    int bp = 0;
#pragma unroll
    for (int p = 1; p < NTAG; ++p) {
      if (v[p] > bv) { bv = v[p]; bp = p; }
    }
    if (act) {
      fv = bv + ft;
      bpL[t * NTAG + k] = (unsigned char)bp;
    }
    ft = ftn;
  }
  float term = act ? (fv + trans[STOP_TAG * NTAG + k]) : NEGV;
  if (k == START_TAG || k == STOP_TAG) term = NEGV;
  float bs = __shfl(term, 0, 64);
  int bk = 0;
#pragma unroll
  for (int p = 1; p < NTAG; ++p) {
    float vv = __shfl(term, p, 64);
    if (vv > bs) { bs = vv; bk = p; }
  }
  if (k == 0) {
    out[0] = bs;
    int cur = bk;
    for (int t = T_LEN - 1; t >= 0; --t) {
      out[1 + t] = (float)cur;
      cur = bpL[t * NTAG + cur];
    }
  }
}

// ---------------------------------------------------------------------------
extern "C" void kernel_launch(void* const* d_in, const int* in_sizes, int n_in,
                              void* d_out, int out_size, void* d_ws,
                              size_t ws_size, hipStream_t stream) {
  const int* words0 = (const int*)d_in[0];
  const int* words1 = (const int*)d_in[1];
  const int* words2 = (const int*)d_in[2];
  const int* words3 = (const int*)d_in[3];
  const float* W_emb  = (const float*)d_in[4];
  const float* w_ih_f = (const float*)d_in[5];
  const float* w_hh_f = (const float*)d_in[6];
  const float* b_ih_f = (const float*)d_in[7];
  const float* b_hh_f = (const float*)d_in[8];
  const float* w_ih_b = (const float*)d_in[9];
  const float* w_hh_b = (const float*)d_in[10];
  const float* b_ih_b = (const float*)d_in[11];
  const float* b_hh_b = (const float*)d_in[12];
  const float* W_tag  = (const float*)d_in[13];
  const float* b_tag  = (const float*)d_in[14];
  const float* trans  = (const float*)d_in[15];

  char* ws = (char*)d_ws;
  float* xg    = (float*)(ws);               // 4096*2048 f32 = 33,554,432 B
  float* hf    = (float*)(ws + 33554432);    // 4096*256 f32  =  4,194,304 B
  float* hb    = (float*)(ws + 37748736);    // 4096*256 f32  =  4,194,304 B
  int*   qw    = (int*)  (ws + 41943040);    // 2048*64 i32   =    524,288 B
  float* fac   = (float*)(ws + 42467328);    // 2048 f32
  float* feats = (float*)(ws + 42475520);    // 4096*12 f32

  quant_whh<<<dim3(2048), dim3(64), 0, stream>>>(w_hh_f, w_hh_b, qw, fac);
  xg_gemm<<<dim3(32, 32), dim3(256), 0, stream>>>(
      words0, words1, words2, words3, W_emb, w_ih_f, w_ih_b, b_ih_f, b_hh_f,
      b_ih_b, b_hh_b, xg);
  lstm_rec<<<dim3(2), dim3(256), 0, stream>>>(xg, qw, fac, hf, hb);
  feats_k<<<dim3(12288), dim3(256), 0, stream>>>(W_tag, b_tag, hf, hb, feats);
  viterbi_k<<<dim3(1), dim3(64), 0, stream>>>(feats, trans, (float*)d_out);
}

// Round 2
// 6051.694 us; speedup vs baseline: 1.1901x; 1.1901x over previous
//
#include <hip/hip_runtime.h>
#include <math.h>

#define T_LEN 4096
#define EMB 300
#define DIN 1200
#define HID 256
#define G4 1024           // 4*HID gate rows per direction
#define NTAG 12
#define START_TAG 10
#define STOP_TAG 11
#define NEGV -10000.0f

#if defined(__has_builtin)
#  if __has_builtin(__builtin_amdgcn_sdot4)
#    define HAVE_SDOT4 1
#  endif
#endif

__device__ __forceinline__ int sdot4(int a, int b, int c) {
#ifdef HAVE_SDOT4
  return __builtin_amdgcn_sdot4(a, b, c, false);
#else
  return c + (int)(char)(a) * (int)(char)(b)
           + (int)(char)(a >> 8) * (int)(char)(b >> 8)
           + (int)(char)(a >> 16) * (int)(char)(b >> 16)
           + (a >> 24) * (b >> 24);
#endif
}

__device__ __forceinline__ float sigm(float x) { return 1.0f / (1.0f + __expf(-x)); }
__device__ __forceinline__ float tanh_fast(float x) {
  x = fminf(fmaxf(x, -15.0f), 15.0f);
  float e = __expf(2.0f * x);
  return (e - 1.0f) / (e + 1.0f);
}

// ---------------------------------------------------------------------------
// Quantize w_hh (both directions) to int8, per-row scale. Row r: 256 f32 ->
// 64 packed int32 (little-endian byte order matches v_dot4_i32_i8).
// fac[row] = maxabs/(127*127): preact_rec = fac * (int32 dot of qw,qh).
// ---------------------------------------------------------------------------
__global__ __launch_bounds__(64) void quant_whh(const float* __restrict__ w_hh_f,
                                                const float* __restrict__ w_hh_b,
                                                int* __restrict__ qw,
                                                float* __restrict__ fac) {
  int row = blockIdx.x;   // 0..2047 (fwd rows 0..1023, bwd 1024..2047)
  int tid = threadIdx.x;  // 0..63
  const float* src = (row < G4) ? (w_hh_f + (size_t)row * HID)
                                : (w_hh_b + (size_t)(row - G4) * HID);
  float4 v = *(const float4*)(src + tid * 4);
  float m = fmaxf(fmaxf(fabsf(v.x), fabsf(v.y)), fmaxf(fabsf(v.z), fabsf(v.w)));
#pragma unroll
  for (int off = 32; off > 0; off >>= 1) m = fmaxf(m, __shfl_xor(m, off, 64));
  float inv = (m > 0.f) ? 127.0f / m : 0.f;
  int q0 = (int)rintf(v.x * inv), q1 = (int)rintf(v.y * inv);
  int q2 = (int)rintf(v.z * inv), q3 = (int)rintf(v.w * inv);
  qw[(size_t)row * 64 + tid] =
      (q0 & 255) | ((q1 & 255) << 8) | ((q2 & 255) << 16) | ((q3 & 255) << 24);
  if (tid == 0) fac[row] = m / (127.0f * 127.0f);
}

// ---------------------------------------------------------------------------
// xg[t][j] = emb_row(t) . w_ih[j] + b_ih[j] + b_hh[j];  j<1024 fwd, else bwd.
// ---------------------------------------------------------------------------
__global__ __launch_bounds__(256) void xg_gemm(
    const int* __restrict__ words0, const int* __restrict__ words1,
    const int* __restrict__ words2, const int* __restrict__ words3,
    const float* __restrict__ W_emb,
    const float* __restrict__ w_ih_f, const float* __restrict__ w_ih_b,
    const float* __restrict__ b_ih_f, const float* __restrict__ b_hh_f,
    const float* __restrict__ b_ih_b, const float* __restrict__ b_hh_b,
    float* __restrict__ xg) {
  __shared__ __align__(16) float As[16][132];
  __shared__ __align__(16) float Bs[16][68];
  __shared__ int w4[128][4];
  int tid = threadIdx.x;
  int t0 = blockIdx.x * 128;
  int n0 = blockIdx.y * 64;
  if (tid < 128) {
    int t = t0 + tid;
    w4[tid][0] = words0[t]; w4[tid][1] = words1[t];
    w4[tid][2] = words2[t]; w4[tid][3] = words3[t];
  }
  int kq = tid & 3;
  int r  = tid >> 2;
  const float* Bp = (n0 < G4) ? (w_ih_f + (size_t)(n0 + r) * DIN)
                              : (w_ih_b + (size_t)(n0 + r - G4) * DIN);
  float acc[8][4];
#pragma unroll
  for (int m = 0; m < 8; ++m)
#pragma unroll
    for (int n = 0; n < 4; ++n) acc[m][n] = 0.f;
  __syncthreads();

  for (int it = 0; it < 75; ++it) {
    int kk = it * 16 + kq * 4;
    int seg = (kk >= 900) ? 3 : (kk >= 600) ? 2 : (kk >= 300) ? 1 : 0;
    int col = kk - seg * 300;
    int wid0 = w4[r][seg];
    int wid1 = w4[r + 64][seg];
    float4 a0 = *(const float4*)(W_emb + (size_t)wid0 * EMB + col);
    float4 a1 = *(const float4*)(W_emb + (size_t)wid1 * EMB + col);
    float4 b  = *(const float4*)(Bp + kk);
    As[kq * 4 + 0][r] = a0.x; As[kq * 4 + 1][r] = a0.y;
    As[kq * 4 + 2][r] = a0.z; As[kq * 4 + 3][r] = a0.w;
    As[kq * 4 + 0][r + 64] = a1.x; As[kq * 4 + 1][r + 64] = a1.y;
    As[kq * 4 + 2][r + 64] = a1.z; As[kq * 4 + 3][r + 64] = a1.w;
    Bs[kq * 4 + 0][r] = b.x; Bs[kq * 4 + 1][r] = b.y;
    Bs[kq * 4 + 2][r] = b.z; Bs[kq * 4 + 3][r] = b.w;
    __syncthreads();
    int ii = (tid & 15) * 8;
    int jj = (tid >> 4) * 4;
#pragma unroll
    for (int k2 = 0; k2 < 16; ++k2) {
      float4 av0 = *(const float4*)&As[k2][ii];
      float4 av1 = *(const float4*)&As[k2][ii + 4];
      float4 bv  = *(const float4*)&Bs[k2][jj];
      float a[8] = {av0.x, av0.y, av0.z, av0.w, av1.x, av1.y, av1.z, av1.w};
      float bb[4] = {bv.x, bv.y, bv.z, bv.w};
#pragma unroll
      for (int m = 0; m < 8; ++m)
#pragma unroll
        for (int n = 0; n < 4; ++n) acc[m][n] = fmaf(a[m], bb[n], acc[m][n]);
    }
    __syncthreads();
  }
  int ii = (tid & 15) * 8;
  int jj = (tid >> 4) * 4;
  float bias[4];
#pragma unroll
  for (int n = 0; n < 4; ++n) {
    int jg = n0 + jj + n;
    bias[n] = (jg < G4) ? (b_ih_f[jg] + b_hh_f[jg])
                        : (b_ih_b[jg - G4] + b_hh_b[jg - G4]);
  }
#pragma unroll
  for (int m = 0; m < 8; ++m) {
    int row = t0 + ii + m;
    float4 st = make_float4(acc[m][0] + bias[0], acc[m][1] + bias[1],
                            acc[m][2] + bias[2], acc[m][3] + bias[3]);
    *(float4*)(xg + (size_t)row * 2048 + n0 + jj) = st;
  }
}

// ---------------------------------------------------------------------------
// LSTM recurrence v2. One block per direction, 512 threads (8 waves,
// 2 waves/SIMD for latency hiding). Lane pair (2k, 2k+1) in the SAME wave
// owns hidden unit k; each thread holds HALF of all four gate rows as
// 32 NAMED int4 registers (SROA-safe -> truly resident, fixes the round-1
// scratch spill at VGPR_Count=148). Halves combine with one integer
// __shfl_xor per gate (bit-exact vs round 1). h shared as packed int8 in
// LDS, double-buffered -> one barrier/step.
// ---------------------------------------------------------------------------
#define D4(W, H, A)                                         \
  A = sdot4(W.x, H.x, A); A = sdot4(W.y, H.y, A);           \
  A = sdot4(W.z, H.z, A); A = sdot4(W.w, H.w, A);

__global__ __launch_bounds__(512, 2) void lstm_rec(
    const float* __restrict__ xg, const int* __restrict__ qw,
    const float* __restrict__ fac, float* __restrict__ hf,
    float* __restrict__ hb) {
  int dir = blockIdx.x;
  int tid = threadIdx.x;
  int k = tid >> 1;        // hidden unit 0..255
  int half = tid & 1;      // K-half 0..1 (partner lane is tid^1, same wave)
  __shared__ __align__(16) int hq[2][64];   // packed int8 h, double-buffered

  const int* wb0 = qw + (size_t)(dir * G4 + 0 * HID + k) * 64 + half * 32;
  const int* wb1 = qw + (size_t)(dir * G4 + 1 * HID + k) * 64 + half * 32;
  const int* wb2 = qw + (size_t)(dir * G4 + 2 * HID + k) * 64 + half * 32;
  const int* wb3 = qw + (size_t)(dir * G4 + 3 * HID + k) * 64 + half * 32;
  int4 w0a = *(const int4*)(wb0 + 0),  w0b = *(const int4*)(wb0 + 4);
  int4 w0c = *(const int4*)(wb0 + 8),  w0d = *(const int4*)(wb0 + 12);
  int4 w0e = *(const int4*)(wb0 + 16), w0f = *(const int4*)(wb0 + 20);
  int4 w0g = *(const int4*)(wb0 + 24), w0h = *(const int4*)(wb0 + 28);
  int4 w1a = *(const int4*)(wb1 + 0),  w1b = *(const int4*)(wb1 + 4);
  int4 w1c = *(const int4*)(wb1 + 8),  w1d = *(const int4*)(wb1 + 12);
  int4 w1e = *(const int4*)(wb1 + 16), w1f = *(const int4*)(wb1 + 20);
  int4 w1g = *(const int4*)(wb1 + 24), w1h = *(const int4*)(wb1 + 28);
  int4 w2a = *(const int4*)(wb2 + 0),  w2b = *(const int4*)(wb2 + 4);
  int4 w2c = *(const int4*)(wb2 + 8),  w2d = *(const int4*)(wb2 + 12);
  int4 w2e = *(const int4*)(wb2 + 16), w2f = *(const int4*)(wb2 + 20);
  int4 w2g = *(const int4*)(wb2 + 24), w2h = *(const int4*)(wb2 + 28);
  int4 w3a = *(const int4*)(wb3 + 0),  w3b = *(const int4*)(wb3 + 4);
  int4 w3c = *(const int4*)(wb3 + 8),  w3d = *(const int4*)(wb3 + 12);
  int4 w3e = *(const int4*)(wb3 + 16), w3f = *(const int4*)(wb3 + 20);
  int4 w3g = *(const int4*)(wb3 + 24), w3h = *(const int4*)(wb3 + 28);

  float fr0 = fac[dir * G4 + 0 * HID + k];
  float fr1 = fac[dir * G4 + 1 * HID + k];
  float fr2 = fac[dir * G4 + 2 * HID + k];
  float fr3 = fac[dir * G4 + 3 * HID + k];

  float* hout = dir ? hb : hf;
  const float* xbase = xg + dir * G4;
  float c = 0.f;
  if (tid < 64) hq[0][tid] = 0;
  __syncthreads();

  float xv0, xv1, xv2, xv3;
  {
    int t = dir ? (T_LEN - 1) : 0;
    const float* xp = xbase + (size_t)t * 2048 + k;
    xv0 = xp[0]; xv1 = xp[HID]; xv2 = xp[2 * HID]; xv3 = xp[3 * HID];
  }

  for (int s = 0; s < T_LEN; ++s) {
    int t = dir ? (T_LEN - 1 - s) : s;
    // prefetch next step's xg values (independent of h -> in flight during dot)
    float xn0 = 0.f, xn1 = 0.f, xn2 = 0.f, xn3 = 0.f;
    if (s + 1 < T_LEN) {
      int tn = dir ? (T_LEN - 2 - s) : (s + 1);
      const float* xp = xbase + (size_t)tn * 2048 + k;
      xn0 = xp[0]; xn1 = xp[HID]; xn2 = xp[2 * HID]; xn3 = xp[3 * HID];
    }
    const int4* hc = (const int4*)(&hq[s & 1][half * 32]);
    int4 hv0 = hc[0], hv1 = hc[1], hv2 = hc[2], hv3 = hc[3];
    int4 hv4 = hc[4], hv5 = hc[5], hv6 = hc[6], hv7 = hc[7];
    int a0 = 0, a1 = 0, a2 = 0, a3 = 0;
    D4(w0a, hv0, a0) D4(w1a, hv0, a1) D4(w2a, hv0, a2) D4(w3a, hv0, a3)
    D4(w0b, hv1, a0) D4(w1b, hv1, a1) D4(w2b, hv1, a2) D4(w3b, hv1, a3)
    D4(w0c, hv2, a0) D4(w1c, hv2, a1) D4(w2c, hv2, a2) D4(w3c, hv2, a3)
    D4(w0d, hv3, a0) D4(w1d, hv3, a1) D4(w2d, hv3, a2) D4(w3d, hv3, a3)
    D4(w0e, hv4, a0) D4(w1e, hv4, a1) D4(w2e, hv4, a2) D4(w3e, hv4, a3)
    D4(w0f, hv5, a0) D4(w1f, hv5, a1) D4(w2f, hv5, a2) D4(w3f, hv5, a3)
    D4(w0g, hv6, a0) D4(w1g, hv6, a1) D4(w2g, hv6, a2) D4(w3g, hv6, a3)
    D4(w0h, hv7, a0) D4(w1h, hv7, a1) D4(w2h, hv7, a2) D4(w3h, hv7, a3)
    // combine K-halves within the lane pair (integer adds: bit-exact)
    a0 += __shfl_xor(a0, 1, 64);
    a1 += __shfl_xor(a1, 1, 64);
    a2 += __shfl_xor(a2, 1, 64);
    a3 += __shfl_xor(a3, 1, 64);

    float pi = xv0 + fr0 * (float)a0;
    float pf = xv1 + fr1 * (float)a1;
    float pg = xv2 + fr2 * (float)a2;
    float po = xv3 + fr3 * (float)a3;
    float iv = sigm(pi), fg = sigm(pf), gv = tanh_fast(pg), ov = sigm(po);
    c = fg * c + iv * gv;
    float h = ov * tanh_fast(c);
    int qh = (int)rintf(h * 127.0f);
    if (half == 0) {
      hout[(size_t)t * HID + k] = h;
      ((char*)(&hq[(s + 1) & 1][0]))[k] = (char)qh;
    }
    xv0 = xn0; xv1 = xn1; xv2 = xn2; xv3 = xn3;
    __syncthreads();  // next buffer published; old buffer free to overwrite
  }
}

// ---------------------------------------------------------------------------
// feats[t][k] = W_tag[k] . [hf[t]; hb[t]] + b_tag[k]; one wave per (t,k).
// ---------------------------------------------------------------------------
__global__ __launch_bounds__(256) void feats_k(const float* __restrict__ W_tag,
                                               const float* __restrict__ b_tag,
                                               const float* __restrict__ hf,
                                               const float* __restrict__ hb,
                                               float* __restrict__ feats) {
  int pair = blockIdx.x * 4 + (threadIdx.x >> 6);
  int lane = threadIdx.x & 63;
  int t = pair / NTAG;
  int k = pair % NTAG;
  float s = 0.f;
#pragma unroll
  for (int i = 0; i < 4; ++i) {
    int j = i * 64 + lane;
    s = fmaf(W_tag[k * 512 + j], hf[(size_t)t * HID + j], s);
  }
#pragma unroll
  for (int i = 4; i < 8; ++i) {
    int j = i * 64 + lane;
    s = fmaf(W_tag[k * 512 + j], hb[(size_t)t * HID + (j - 256)], s);
  }
#pragma unroll
  for (int off = 32; off > 0; off >>= 1) s += __shfl_xor(s, off, 64);
  if (lane == 0) feats[t * NTAG + k] = s + b_tag[k];
}

// ---------------------------------------------------------------------------
// Viterbi: lane k (<12) holds fv[k]; strict-> ascending scans match
// jnp.argmax first-max tie semantics. Backpointers in LDS; lane-0 backtrace.
// Output: d_out[0]=score, d_out[1..4096]=path (as f32).
// ---------------------------------------------------------------------------
__global__ __launch_bounds__(64) void viterbi_k(const float* __restrict__ feats,
                                                const float* __restrict__ trans,
                                                float* __restrict__ out) {
  __shared__ unsigned char bpL[T_LEN * NTAG];
  int k = threadIdx.x;
  bool act = k < NTAG;
  float trc[NTAG];
#pragma unroll
  for (int p = 0; p < NTAG; ++p) trc[p] = act ? trans[k * NTAG + p] : NEGV;
  float fv = (act && k == START_TAG) ? 0.f : NEGV;
  float ft = act ? feats[k] : 0.f;
  for (int t = 0; t < T_LEN; ++t) {
    float ftn = (act && t + 1 < T_LEN) ? feats[(t + 1) * NTAG + k] : 0.f;
    float v[NTAG];
#pragma unroll
    for (int p = 0; p < NTAG; ++p) v[p] = __shfl(fv, p, 64) + trc[p];
    float bv = v[0];
    int bp = 0;
#pragma unroll
    for (int p = 1; p < NTAG; ++p) {
      if (v[p] > bv) { bv = v[p]; bp = p; }
    }
    if (act) {
      fv = bv + ft;
      bpL[t * NTAG + k] = (unsigned char)bp;
    }
    ft = ftn;
  }
  float term = act ? (fv + trans[STOP_TAG * NTAG + k]) : NEGV;
  if (k == START_TAG || k == STOP_TAG) term = NEGV;
  float bs = __shfl(term, 0, 64);
  int bk = 0;
#pragma unroll
  for (int p = 1; p < NTAG; ++p) {
    float vv = __shfl(term, p, 64);
    if (vv > bs) { bs = vv; bk = p; }
  }
  if (k == 0) {
    out[0] = bs;
    int cur = bk;
    for (int t = T_LEN - 1; t >= 0; --t) {
      out[1 + t] = (float)cur;
      cur = bpL[t * NTAG + cur];
    }
  }
}

// ---------------------------------------------------------------------------
extern "C" void kernel_launch(void* const* d_in, const int* in_sizes, int n_in,
                              void* d_out, int out_size, void* d_ws,
                              size_t ws_size, hipStream_t stream) {
  const int* words0 = (const int*)d_in[0];
  const int* words1 = (const int*)d_in[1];
  const int* words2 = (const int*)d_in[2];
  const int* words3 = (const int*)d_in[3];
  const float* W_emb  = (const float*)d_in[4];
  const float* w_ih_f = (const float*)d_in[5];
  const float* w_hh_f = (const float*)d_in[6];
  const float* b_ih_f = (const float*)d_in[7];
  const float* b_hh_f = (const float*)d_in[8];
  const float* w_ih_b = (const float*)d_in[9];
  const float* w_hh_b = (const float*)d_in[10];
  const float* b_ih_b = (const float*)d_in[11];
  const float* b_hh_b = (const float*)d_in[12];
  const float* W_tag  = (const float*)d_in[13];
  const float* b_tag  = (const float*)d_in[14];
  const float* trans  = (const float*)d_in[15];

  char* ws = (char*)d_ws;
  float* xg    = (float*)(ws);               // 4096*2048 f32 = 33,554,432 B
  float* hf    = (float*)(ws + 33554432);    // 4096*256 f32  =  4,194,304 B
  float* hb    = (float*)(ws + 37748736);    // 4096*256 f32  =  4,194,304 B
  int*   qw    = (int*)  (ws + 41943040);    // 2048*64 i32   =    524,288 B
  float* fac   = (float*)(ws + 42467328);    // 2048 f32
  float* feats = (float*)(ws + 42475520);    // 4096*12 f32

  quant_whh<<<dim3(2048), dim3(64), 0, stream>>>(w_hh_f, w_hh_b, qw, fac);
  xg_gemm<<<dim3(32, 32), dim3(256), 0, stream>>>(
      words0, words1, words2, words3, W_emb, w_ih_f, w_ih_b, b_ih_f, b_hh_f,
      b_ih_b, b_hh_b, xg);
  lstm_rec<<<dim3(2), dim3(512), 0, stream>>>(xg, qw, fac, hf, hb);
  feats_k<<<dim3(12288), dim3(256), 0, stream>>>(W_tag, b_tag, hf, hb, feats);
  viterbi_k<<<dim3(1), dim3(64), 0, stream>>>(feats, trans, (float*)d_out);
}